// Round 5
// baseline (190.856 us; speedup 1.0000x reference)
//
#include <hip/hip_runtime.h>

#define NN 8192
#define FIN 512
#define FO 64

typedef short bf16x8 __attribute__((ext_vector_type(8)));
typedef float f32x4 __attribute__((ext_vector_type(4)));

union AFrag { bf16x8 v; __bf16 b[8]; };

// ---------------- kernel 0: W[512][64] f32 -> WT[64][512] bf16 (LDS transpose)
__global__ __launch_bounds__(512) void wt_kernel(const float* __restrict__ W, __bf16* __restrict__ WT) {
    __shared__ float tile[64][65];
    const int k0 = blockIdx.x * 64;
    #pragma unroll
    for (int r = 0; r < 8; ++r) {
        const int kl = r * 8 + (threadIdx.x >> 6);
        const int f  = threadIdx.x & 63;
        tile[kl][f] = W[(size_t)(k0 + kl) * FO + f];
    }
    __syncthreads();
    const int f   = threadIdx.x >> 3;
    const int kk8 = (threadIdx.x & 7) * 8;
    unsigned u[4];
    #pragma unroll
    for (int h = 0; h < 4; ++h) {
        union { __bf16 b; unsigned short us; } lo, hi;
        lo.b = (__bf16)tile[kk8 + 2*h][f];
        hi.b = (__bf16)tile[kk8 + 2*h + 1][f];
        u[h] = (unsigned)lo.us | ((unsigned)hi.us << 16);
    }
    *(uint4*)(WT + (size_t)f * FIN + k0 + kk8) = make_uint4(u[0], u[1], u[2], u[3]);
}

// ---------------- kernel 1: Wh = x@W (bf16 MFMA), emit swizzled Wh + s + t ---
// whs layout: per 32-col block jb, per ft (0..3), per lane l: uint4 = 8 bf16
// B-fragment elems for mfma_f32_16x16x32_bf16. (verified R1-R4)
__global__ __launch_bounds__(128) void wh_kernel(
    const float* __restrict__ x, const __bf16* __restrict__ WT,
    const float* __restrict__ a, uint4* __restrict__ whs,
    float* __restrict__ s_out, float* __restrict__ t_out)
{
    __shared__ float whlds[2][16][FO + 1];
    const int w  = threadIdx.x >> 6;
    const int l  = threadIdx.x & 63;
    const int lr = l & 15, lg = l >> 4;
    const int rb = (blockIdx.x * 2 + w) * 16;

    f32x4 acc[4] = {};
    const float* xr = x + (size_t)(rb + lr) * FIN;
    const __bf16* wbase[4];
    #pragma unroll
    for (int ft = 0; ft < 4; ++ft) wbase[ft] = WT + (ft*16 + lr) * FIN;

    float4 nxa = *(const float4*)(xr + lg*4);
    float4 nxb = *(const float4*)(xr + lg*4 + 16);
    for (int ks = 0; ks < 16; ++ks) {
        const int k0 = ks*32 + lg*4;
        const float4 xa = nxa, xb = nxb;
        const int kn = (ks < 15 ? ks + 1 : 15)*32 + lg*4;
        nxa = *(const float4*)(xr + kn);
        nxb = *(const float4*)(xr + kn + 16);
        AFrag af;
        af.b[0]=(__bf16)xa.x; af.b[1]=(__bf16)xa.y; af.b[2]=(__bf16)xa.z; af.b[3]=(__bf16)xa.w;
        af.b[4]=(__bf16)xb.x; af.b[5]=(__bf16)xb.y; af.b[6]=(__bf16)xb.z; af.b[7]=(__bf16)xb.w;
        #pragma unroll
        for (int ft = 0; ft < 4; ++ft) {
            union { bf16x8 v; uint2 q[2]; } bf;
            bf.q[0] = *(const uint2*)(wbase[ft] + k0);
            bf.q[1] = *(const uint2*)(wbase[ft] + k0 + 16);
            acc[ft] = __builtin_amdgcn_mfma_f32_16x16x32_bf16(af.v, bf.v, acc[ft], 0, 0, 0);
        }
    }

    #pragma unroll
    for (int ft = 0; ft < 4; ++ft)
        #pragma unroll
        for (int q = 0; q < 4; ++q)
            whlds[w][lg*4+q][ft*16+lr] = acc[ft][q];

    float sp[4] = {0,0,0,0}, tp[4] = {0,0,0,0};
    #pragma unroll
    for (int ft = 0; ft < 4; ++ft) {
        const float a1 = a[ft*16 + lr];
        const float a2 = a[FO + ft*16 + lr];
        #pragma unroll
        for (int q = 0; q < 4; ++q) { sp[q] += acc[ft][q]*a1; tp[q] += acc[ft][q]*a2; }
    }
    #pragma unroll
    for (int d = 1; d < 16; d <<= 1) {
        #pragma unroll
        for (int q = 0; q < 4; ++q) { sp[q] += __shfl_xor(sp[q], d); tp[q] += __shfl_xor(tp[q], d); }
    }
    if (lr == 0) {
        *(float4*)(s_out + rb + lg*4) = make_float4(sp[0], sp[1], sp[2], sp[3]);
        *(float4*)(t_out + rb + lg*4) = make_float4(tp[0], tp[1], tp[2], tp[3]);
    }

    __syncthreads();

    const int jb = blockIdx.x;
    #pragma unroll
    for (int q = 0; q < 2; ++q) {
        const int ft = w*2 + q;
        const int f  = ft*16 + lr;
        unsigned u[4];
        #pragma unroll
        for (int h = 0; h < 4; ++h) {
            const int c0 = ((h & 2) ? 16 : 0) + lg*4 + (h & 1)*2;
            union { __bf16 b; unsigned short us; } lo, hi;
            lo.b = (__bf16)whlds[c0 >> 4][c0 & 15][f];
            hi.b = (__bf16)whlds[(c0+1) >> 4][(c0+1) & 15][f];
            u[h] = (unsigned)lo.us | ((unsigned)hi.us << 16);
        }
        whs[(jb*4 + ft)*64 + l] = make_uint4(u[0], u[1], u[2], u[3]);
    }
}

// ---------------- kernel 2: adj (256 MB) -> row-major bitmask (8 MB) --------
// addr = g*64 + lane is PURE LINEAR grid-stride (fill-kernel shape).
// mask[row*256 + jw] = bits for cols jw*32..+31 of row (bit c = adj!=0).
__global__ __launch_bounds__(256) void mask_kernel(
    const int* __restrict__ adj, unsigned* __restrict__ mask)
{
    const int l   = threadIdx.x & 63;
    const int wid = (blockIdx.x * 256 + threadIdx.x) >> 6;   // 0..4095
    #pragma unroll 4
    for (int g = wid; g < NN * 128; g += 4096) {
        const int v = adj[(size_t)g * 64 + l];
        const unsigned long long b = __ballot(v != 0);
        if (l == 0)
            *(uint2*)(mask + (size_t)g * 2) = make_uint2((unsigned)b, (unsigned)(b >> 32));
    }
}

// ---------------- kernel 3: compute-bound fused GAT ----------------
// 256 blocks x 1024 thr = 16 independent K-waves. Block owns 32 rows; wave w
// owns cols [w*512, +512): 16 iters of 32 cols. Per iter: 2 mask words ->
// 16 exps/lane -> 2 A-frags (rows 0-15, 16-31) -> 8 MFMA vs shared bv.
// No barriers in the main loop; K-reduce via LDS tree at the end.
__global__ __launch_bounds__(1024, 4) void gat3_kernel(
    const unsigned* __restrict__ mask, const uint4* __restrict__ whs,
    const float* __restrict__ s_in, const float* __restrict__ t_in,
    float* __restrict__ out)
{
    __shared__ float red[8][2048];     // 64 KB reduce buffer
    __shared__ float dnl[16][32];
    __shared__ float dns[32];
    const int w  = threadIdx.x >> 6;   // 0..15
    const int l  = threadIdx.x & 63;
    const int lr = l & 15, lg = l >> 4;
    const int rg = blockIdx.x;
    const int r0 = rg * 32;
    const float sA = s_in[r0 + lr];
    const float sB = s_in[r0 + 16 + lr];
    const unsigned* mrowA = mask + (size_t)(r0 + lr) * 256;
    const unsigned* mrowB = mask + (size_t)(r0 + 16 + lr) * 256;
    const int sh0 = lg * 4;
    const bf16x8* wv = (const bf16x8*)whs;

    f32x4 acc[2][4] = {};
    float dnA = 0.f, dnB = 0.f;

    // 1-deep prefetch of mask/t (exp chain depends on them immediately)
    unsigned mA = mrowA[w*16], mB = mrowB[w*16];
    float4 t0 = *(const float4*)(t_in + w*512 + sh0);
    float4 t1 = *(const float4*)(t_in + w*512 + 16 + sh0);

    for (int it = 0; it < 16; ++it) {
        const int jb = w*16 + it;
        // bv for current iter: consumed only after the exp chain (~250 cyc)
        bf16x8 bv0 = wv[(jb*4 + 0)*64 + l];
        bf16x8 bv1 = wv[(jb*4 + 1)*64 + l];
        bf16x8 bv2 = wv[(jb*4 + 2)*64 + l];
        bf16x8 bv3 = wv[(jb*4 + 3)*64 + l];
        // next-iter mask/t
        const int jn = w*16 + (it + 1 < 16 ? it + 1 : 15);
        const unsigned nmA = mrowA[jn], nmB = mrowB[jn];
        const float4 nt0 = *(const float4*)(t_in + jn*32 + sh0);
        const float4 nt1 = *(const float4*)(t_in + jn*32 + 16 + sh0);

        const float tv[8] = {t0.x, t0.y, t0.z, t0.w, t1.x, t1.y, t1.z, t1.w};
        AFrag afA, afB;
        #pragma unroll
        for (int e = 0; e < 8; ++e) {
            const int bit = (e < 4) ? (sh0 + e) : (12 + sh0 + e);  // 16+sh0+(e-4)
            float eA = sA + tv[e]; eA = fmaxf(eA, 0.2f * eA);
            float eB = sB + tv[e]; eB = fmaxf(eB, 0.2f * eB);
            const float pA = ((mA >> bit) & 1u) ? __expf(eA) : 0.f;
            const float pB = ((mB >> bit) & 1u) ? __expf(eB) : 0.f;
            dnA += pA; dnB += pB;
            afA.b[e] = (__bf16)pA;
            afB.b[e] = (__bf16)pB;
        }
        acc[0][0] = __builtin_amdgcn_mfma_f32_16x16x32_bf16(afA.v, bv0, acc[0][0], 0, 0, 0);
        acc[0][1] = __builtin_amdgcn_mfma_f32_16x16x32_bf16(afA.v, bv1, acc[0][1], 0, 0, 0);
        acc[0][2] = __builtin_amdgcn_mfma_f32_16x16x32_bf16(afA.v, bv2, acc[0][2], 0, 0, 0);
        acc[0][3] = __builtin_amdgcn_mfma_f32_16x16x32_bf16(afA.v, bv3, acc[0][3], 0, 0, 0);
        acc[1][0] = __builtin_amdgcn_mfma_f32_16x16x32_bf16(afB.v, bv0, acc[1][0], 0, 0, 0);
        acc[1][1] = __builtin_amdgcn_mfma_f32_16x16x32_bf16(afB.v, bv1, acc[1][1], 0, 0, 0);
        acc[1][2] = __builtin_amdgcn_mfma_f32_16x16x32_bf16(afB.v, bv2, acc[1][2], 0, 0, 0);
        acc[1][3] = __builtin_amdgcn_mfma_f32_16x16x32_bf16(afB.v, bv3, acc[1][3], 0, 0, 0);

        mA = nmA; mB = nmB; t0 = nt0; t1 = nt1;
    }

    // per-row denominators: sum the 4 lane-groups of this wave
    dnA += __shfl_xor(dnA, 16); dnA += __shfl_xor(dnA, 32);
    dnB += __shfl_xor(dnB, 16); dnB += __shfl_xor(dnB, 32);
    if (l < 16) { dnl[w][l] = dnA; dnl[w][16 + l] = dnB; }
    __syncthreads();
    if (threadIdx.x < 32) {
        float s = 0.f;
        #pragma unroll
        for (int ww = 0; ww < 16; ++ww) s += dnl[ww][threadIdx.x];
        dns[threadIdx.x] = s;
    }

    // K-reduce acc across 16 waves (tree)
    for (int h = 8; h >= 1; h >>= 1) {
        if (w >= h && w < 2*h) {
            #pragma unroll
            for (int g = 0; g < 2; ++g)
                #pragma unroll
                for (int ft = 0; ft < 4; ++ft)
                    #pragma unroll
                    for (int q = 0; q < 4; ++q)
                        red[w - h][((g*16 + lg*4 + q)*FO) + ft*16 + lr] = acc[g][ft][q];
        }
        __syncthreads();
        if (w < h) {
            #pragma unroll
            for (int g = 0; g < 2; ++g)
                #pragma unroll
                for (int ft = 0; ft < 4; ++ft)
                    #pragma unroll
                    for (int q = 0; q < 4; ++q)
                        acc[g][ft][q] += red[w][((g*16 + lg*4 + q)*FO) + ft*16 + lr];
        }
        __syncthreads();
    }

    // epilogue: wave 0 holds 32x64. C/D map: col(feature)=lr, row m=lg*4+q
    if (w == 0) {
        #pragma unroll
        for (int g = 0; g < 2; ++g) {
            #pragma unroll
            for (int ft = 0; ft < 4; ++ft) {
                #pragma unroll
                for (int q = 0; q < 4; ++q) {
                    const int m = g*16 + lg*4 + q;
                    const float h2 = acc[g][ft][q] / dns[m];
                    out[(size_t)(r0 + m) * FO + ft*16 + lr] =
                        (h2 > 0.f) ? h2 : (__expf(h2) - 1.f);
                }
            }
        }
    }
}

extern "C" void kernel_launch(void* const* d_in, const int* in_sizes, int n_in,
                              void* d_out, int out_size, void* d_ws, size_t ws_size,
                              hipStream_t stream) {
    const float* x   = (const float*)d_in[0];
    const int*   adj = (const int*)d_in[1];
    const float* W   = (const float*)d_in[2];
    const float* a   = (const float*)d_in[3];
    float* out = (float*)d_out;

    char* ws = (char*)d_ws;
    uint4*    whs  = (uint4*)ws;                                   // 1 MiB
    __bf16*   WT   = (__bf16*)(ws + (1u << 20));                   // 64 KiB
    float*    s    = (float*)(ws + (1u << 20) + (1u << 16));       // 32 KiB
    float*    t    = (float*)(ws + (1u << 20) + (1u << 16) + 32768);
    unsigned* mask = (unsigned*)(ws + (2u << 20));                 // 8 MiB

    wt_kernel  <<<8,    512, 0, stream>>>(W, WT);
    wh_kernel  <<<256,  128, 0, stream>>>(x, WT, a, whs, s, t);
    mask_kernel<<<1024, 256, 0, stream>>>(adj, mask);
    gat3_kernel<<<256, 1024, 0, stream>>>(mask, whs, s, t, out);
}